// Round 7
// baseline (165.068 us; speedup 1.0000x reference)
//
#include <hip/hip_runtime.h>

#define N_PTS 8192
#define BATCH 2
#define KNN 8
#define STILE 2048          // smooth LDS tile (points)
#define PPB 16              // smooth points per block (4 waves x 4 pts)
#define CH_R 4              // chamfer rows per thread
#define CH_SLICE 256        // chamfer candidates per block
#define NSLICE (N_PTS / CH_SLICE)   // 32
#define PF 8                // chamfer prefetch depth

// ---- ws layout (bytes) ----
#define OFF_Q1W 0                       // warped pc1, 2*8192 float4 = 256 KiB
#define OFF_Q2  (256*1024)              // pc2 + norm
#define OFF_Q1  (512*1024)              // raw pc1 + norm
#define OFF_MINS (768*1024)             // atomic-fallback mins, 128 KiB
#define OFF_PART (896*1024)             // partial mins, 4 MiB
#define WS_STORE_NEED  (896*1024 + 4*1024*1024)

// ---------------- helpers ----------------
__device__ __forceinline__ void ce(unsigned &x, unsigned &y) {
    unsigned lo = min(x, y), hi = max(x, y); x = lo; y = hi;
}

__device__ __forceinline__ void insert4(unsigned o[4], unsigned key) {
    unsigned n0 = min(o[0], key);
    unsigned n1 = max(o[0], min(o[1], key));
    unsigned n2 = max(o[1], min(o[2], key));
    unsigned n3 = max(o[2], min(o[3], key));
    o[0]=n0; o[1]=n1; o[2]=n2; o[3]=n3;
}

__device__ __forceinline__ void merge_stage8(unsigned m[8], int d) {
    unsigned p[8], c[8];
    #pragma unroll
    for (int k = 0; k < 8; ++k) p[k] = __shfl_xor(m[k], d, 64);
    #pragma unroll
    for (int k = 0; k < 8; ++k) c[k] = min(m[k], p[7-k]);
    ce(c[0],c[4]); ce(c[1],c[5]); ce(c[2],c[6]); ce(c[3],c[7]);
    ce(c[0],c[2]); ce(c[1],c[3]); ce(c[4],c[6]); ce(c[5],c[7]);
    ce(c[0],c[1]); ce(c[2],c[3]); ce(c[4],c[5]); ce(c[6],c[7]);
    #pragma unroll
    for (int k = 0; k < 8; ++k) m[k] = c[k];
}

__device__ __forceinline__ void merge64(unsigned m[8]) {
    merge_stage8(m, 1); merge_stage8(m, 2); merge_stage8(m, 4);
    merge_stage8(m, 8); merge_stage8(m, 16); merge_stage8(m, 32);
}

// ---------------- prep: float4(x,y,z,norm) arrays + out/mins init ----------------
__global__ void prep_kernel(const float* __restrict__ pc1, const float* __restrict__ pc2,
                            const float* __restrict__ flow,
                            float4* __restrict__ q1w, float4* __restrict__ q2f,
                            float4* __restrict__ q1f, unsigned* __restrict__ mins,
                            float* __restrict__ out, int init_mins) {
    int idx = blockIdx.x * 256 + threadIdx.x;   // 0..16383 == b*8192+i
    if (idx == 0) out[0] = 0.0f;
    if (init_mins) { mins[idx] = 0x7F800000u; mins[idx + 16384] = 0x7F800000u; }
    float x1 = pc1[idx*3+0], y1 = pc1[idx*3+1], z1 = pc1[idx*3+2];
    float fx = flow[idx*3+0], fy = flow[idx*3+1], fz = flow[idx*3+2];
    float x2 = pc2[idx*3+0], y2 = pc2[idx*3+1], z2 = pc2[idx*3+2];
    float wx = x1 + fx, wy = y1 + fy, wz = z1 + fz;
    q1w[idx] = make_float4(wx, wy, wz, fmaf(wx, wx, fmaf(wy, wy, wz * wz)));
    q2f[idx] = make_float4(x2, y2, z2, fmaf(x2, x2, fmaf(y2, y2, z2 * z2)));
    q1f[idx] = make_float4(x1, y1, z1, fmaf(x1, x1, fmaf(y1, y1, z1 * z1)));
}

// ---------------- chamfer: no LDS, uniform candidate loads, partial stores ----------------
__global__ __launch_bounds__(256, 4) void chamfer_min_kernel(
        const float4* __restrict__ q1w, const float4* __restrict__ q2f,
        unsigned* __restrict__ mins, float* __restrict__ part, int store_mode) {
    const int z = blockIdx.z;           // combo = dir*2 + b
    const int b = z & 1, dir = z >> 1;
    const int tid = threadIdx.x;
    const float4* rows  = (dir == 0 ? q1w : q2f) + b * N_PTS;
    const float4* cands = (dir == 0 ? q2f : q1w) + b * N_PTS;
    const int m0 = blockIdx.y * CH_SLICE;
    const int i0 = blockIdx.x * (256 * CH_R) + tid * CH_R;

    float mx[CH_R], my_[CH_R], mz_[CH_R], p2[CH_R], best[CH_R];
    #pragma unroll
    for (int r = 0; r < CH_R; ++r) {
        float4 p = rows[i0 + r];
        mx[r] = -2.0f * p.x; my_[r] = -2.0f * p.y; mz_[r] = -2.0f * p.z;
        p2[r] = p.w;
        best[r] = __builtin_inff();
    }

    const float4* Qc = cands + m0;
    float4 q[PF];
    #pragma unroll
    for (int u = 0; u < PF; ++u) q[u] = Qc[u];
    #pragma unroll 1
    for (int g = 0; g < CH_SLICE; g += PF) {
        float4 qn[PF];
        const int nb = (g + PF < CH_SLICE) ? g + PF : 0;
        #pragma unroll
        for (int u = 0; u < PF; ++u) qn[u] = Qc[nb + u];
        #pragma unroll
        for (int u = 0; u < PF; ++u) {
            #pragma unroll
            for (int r = 0; r < CH_R; ++r) {
                float s = fmaf(mx[r], q[u].x, fmaf(my_[r], q[u].y, fmaf(mz_[r], q[u].z, q[u].w)));
                best[r] = fminf(best[r], s);
            }
        }
        #pragma unroll
        for (int u = 0; u < PF; ++u) q[u] = qn[u];
    }

    if (store_mode) {
        float4 v;
        v.x = fmaxf(best[0] + p2[0], 0.0f);
        v.y = fmaxf(best[1] + p2[1], 0.0f);
        v.z = fmaxf(best[2] + p2[2], 0.0f);
        v.w = fmaxf(best[3] + p2[3], 0.0f);
        *(float4*)(part + ((size_t)(z * NSLICE + blockIdx.y)) * N_PTS + i0) = v;
    } else {
        #pragma unroll
        for (int r = 0; r < CH_R; ++r) {
            float d2 = fmaxf(best[r] + p2[r], 0.0f);
            atomicMin(&mins[z * N_PTS + i0 + r], __float_as_uint(d2));
        }
    }
}

// ---------------- chamfer reduce: min over slices, sqrt, mean ----------------
__global__ void chamfer_reduce_kernel(const unsigned* __restrict__ mins,
                                      const float* __restrict__ part,
                                      float* __restrict__ out, int store_mode) {
    int t = blockIdx.x * 256 + threadIdx.x;   // 0..32767 = combo*8192+row
    float v;
    if (store_mode) {
        int c = t >> 13, row = t & (N_PTS - 1);
        const float* p = part + ((size_t)c * NSLICE) * N_PTS + row;
        v = __builtin_inff();
        #pragma unroll 8
        for (int s = 0; s < NSLICE; ++s) v = fminf(v, p[(size_t)s * N_PTS]);
    } else {
        v = __uint_as_float(mins[t]);
    }
    float d = sqrtf(v) * (1.0f / (float)(BATCH * N_PTS));
    #pragma unroll
    for (int off = 32; off > 0; off >>= 1) d += __shfl_down(d, off, 64);
    __shared__ float wsum[4];
    int wid = threadIdx.x >> 6;
    if ((threadIdx.x & 63) == 0) wsum[wid] = d;
    __syncthreads();
    if (threadIdx.x == 0) atomicAdd(out, wsum[0] + wsum[1] + wsum[2] + wsum[3]);
}

// ---------------- smoothness: wave owns 4 points, lane owns candidate slice ----------------
__global__ __launch_bounds__(256, 4) void smooth_kernel(const float4* __restrict__ q1f,
                                                        const float* __restrict__ flow,
                                                        float* __restrict__ out) {
    const int b = blockIdx.y;
    const int tid = threadIdx.x;
    const int wv = tid >> 6, lane = tid & 63;
    const int i0w = blockIdx.x * PPB + wv * 4;
    const float4* Q = q1f + b * N_PTS;
    const float*  F = flow + (size_t)b * N_PTS * 3;

    float mx[4], my[4], mz[4], p2[4], gr[4];
    #pragma unroll
    for (int r = 0; r < 4; ++r) {
        float4 p = Q[i0w + r];
        mx[r] = -2.0f * p.x; my[r] = -2.0f * p.y; mz[r] = -2.0f * p.z;
        p2[r] = p.w;
        gr[r] = __builtin_inff();
    }

    unsigned o[4][4];
    #pragma unroll
    for (int r = 0; r < 4; ++r)
        #pragma unroll
        for (int k = 0; k < 4; ++k) o[r][k] = 0xFFFFFFFFu;

    __shared__ float4 sq[STILE];   // 32 KiB
    __shared__ float psum[4];

    #pragma unroll 1
    for (int tile = 0; tile < N_PTS / STILE; ++tile) {   // 4 tiles
        const int t0 = tile * STILE;
        __syncthreads();
        #pragma unroll
        for (int u = tid; u < STILE; u += 256) sq[u] = Q[t0 + u];
        __syncthreads();

        if (tile == 0) {
            float4 qa = sq[lane];
            #pragma unroll 1
            for (int st = 0; st < STILE / 64; ++st) {
                float4 qb = sq[(((st + 1) & 31) * 64) + lane];
                int j = st * 64 + lane;
                #pragma unroll
                for (int r = 0; r < 4; ++r) {
                    float s = fmaf(mx[r], qa.x, fmaf(my[r], qa.y, fmaf(mz[r], qa.z, qa.w)));
                    float d2 = fmaxf(s + p2[r], 0.0f);
                    unsigned key = (__float_as_uint(d2) & 0xFFFFE000u) | (unsigned)j;
                    insert4(o[r], key);   // self (d2=0) included; removed at end
                }
                qa = qb;
            }
        } else {
            float4 qa = sq[lane];
            #pragma unroll 1
            for (int st = 0; st < STILE / 64; ++st) {
                float4 qb = sq[(((st + 1) & 31) * 64) + lane];
                int j = t0 + st * 64 + lane;
                float s0 = fmaf(mx[0], qa.x, fmaf(my[0], qa.y, fmaf(mz[0], qa.z, qa.w)));
                float s1 = fmaf(mx[1], qa.x, fmaf(my[1], qa.y, fmaf(mz[1], qa.z, qa.w)));
                float s2 = fmaf(mx[2], qa.x, fmaf(my[2], qa.y, fmaf(mz[2], qa.z, qa.w)));
                float s3 = fmaf(mx[3], qa.x, fmaf(my[3], qa.y, fmaf(mz[3], qa.z, qa.w)));
                if (__any(s0 <= gr[0])) {
                    float d2 = fmaxf(s0 + p2[0], 0.0f);
                    insert4(o[0], (__float_as_uint(d2) & 0xFFFFE000u) | (unsigned)j);
                }
                if (__any(s1 <= gr[1])) {
                    float d2 = fmaxf(s1 + p2[1], 0.0f);
                    insert4(o[1], (__float_as_uint(d2) & 0xFFFFE000u) | (unsigned)j);
                }
                if (__any(s2 <= gr[2])) {
                    float d2 = fmaxf(s2 + p2[2], 0.0f);
                    insert4(o[2], (__float_as_uint(d2) & 0xFFFFE000u) | (unsigned)j);
                }
                if (__any(s3 <= gr[3])) {
                    float d2 = fmaxf(s3 + p2[3], 0.0f);
                    insert4(o[3], (__float_as_uint(d2) & 0xFFFFE000u) | (unsigned)j);
                }
                qa = qb;
            }
        }

        if (tile <= 2) {
            // cheap valid thr: min over lane-quads of max(o[2]) bounds the
            // 12th-smallest key (>= 9th incl-self = 8th excl-self). 12 insts/pt.
            #pragma unroll
            for (int r = 0; r < 4; ++r) {
                unsigned a = max(o[r][2], (unsigned)__shfl_xor((int)o[r][2], 1, 64));
                a = max(a, (unsigned)__shfl_xor((int)a, 2, 64));
                a = min(a, (unsigned)__shfl_xor((int)a, 4, 64));
                a = min(a, (unsigned)__shfl_xor((int)a, 8, 64));
                a = min(a, (unsigned)__shfl_xor((int)a, 16, 64));
                a = min(a, (unsigned)__shfl_xor((int)a, 32, 64));
                // +2 truncation-buckets slack: gate passes superset of key<=thr
                float thr_up = __uint_as_float((a & 0xFFFFE000u) + 0x4000u);
                gr[r] = thr_up - p2[r];
            }
        }
    }

    // branchless removal of the self entry (key index == i), then final merge
    #pragma unroll
    for (int r = 0; r < 4; ++r) {
        const unsigned ii = (unsigned)(i0w + r);
        bool m0 = (o[r][0] & 8191u) == ii;
        bool m1 = m0 | ((o[r][1] & 8191u) == ii);
        bool m2 = m1 | ((o[r][2] & 8191u) == ii);
        bool m3 = m2 | ((o[r][3] & 8191u) == ii);
        o[r][0] = m0 ? o[r][1] : o[r][0];
        o[r][1] = m1 ? o[r][2] : o[r][1];
        o[r][2] = m2 ? o[r][3] : o[r][2];
        o[r][3] = m3 ? 0xFFFFFFFFu : o[r][3];
    }

    unsigned fin[4][8];
    #pragma unroll
    for (int r = 0; r < 4; ++r) {
        unsigned m[8] = {o[r][0], o[r][1], o[r][2], o[r][3],
                         0xFFFFFFFFu, 0xFFFFFFFFu, 0xFFFFFFFFu, 0xFFFFFFFFu};
        merge64(m);
        #pragma unroll
        for (int k = 0; k < 8; ++k) fin[r][k] = m[k];
    }

    // lanes 0..31 cover (point r = sel>>3, neighbor k = sel&7); 32..63 duplicate (x2)
    const int sel = lane & 31;
    unsigned key = fin[0][0];
    #pragma unroll
    for (int rr = 0; rr < 4; ++rr)
        #pragma unroll
        for (int kk = 0; kk < 8; ++kk)
            if (sel == rr * 8 + kk) key = fin[rr][kk];
    const int r = sel >> 3;
    const int i = i0w + r;
    const int j = (int)(key & (N_PTS - 1));
    float dx = F[i*3+0] - F[j*3+0];
    float dy = F[i*3+1] - F[j*3+1];
    float dz = F[i*3+2] - F[j*3+2];
    float s = sqrtf(fmaf(dx, dx, fmaf(dy, dy, dz * dz)));
    #pragma unroll
    for (int d = 1; d < 64; d <<= 1) s += __shfl_xor(s, d, 64);
    if (lane == 0) psum[wv] = s;
    __syncthreads();
    if (tid == 0) {
        // W_SMOOTH(0.5) * 1/2 (lane duplication) / (B*N*K)
        atomicAdd(out, (psum[0] + psum[1] + psum[2] + psum[3]) *
                       (0.25f / ((float)BATCH * N_PTS * KNN)));
    }
}

extern "C" void kernel_launch(void* const* d_in, const int* in_sizes, int n_in,
                              void* d_out, int out_size, void* d_ws, size_t ws_size,
                              hipStream_t stream) {
    const float* pc1  = (const float*)d_in[0];
    const float* pc2  = (const float*)d_in[1];
    const float* flow = (const float*)d_in[2];
    float* out = (float*)d_out;
    char* ws = (char*)d_ws;

    float4* q1w  = (float4*)(ws + OFF_Q1W);
    float4* q2f  = (float4*)(ws + OFF_Q2);
    float4* q1f  = (float4*)(ws + OFF_Q1);
    unsigned* mins = (unsigned*)(ws + OFF_MINS);
    float* part  = (float*)(ws + OFF_PART);

    const int store_mode = (ws_size >= (size_t)WS_STORE_NEED) ? 1 : 0;

    prep_kernel<<<dim3(16384 / 256), 256, 0, stream>>>(pc1, pc2, flow, q1w, q2f, q1f,
                                                       mins, out, store_mode ? 0 : 1);

    dim3 gch(N_PTS / (256 * CH_R), NSLICE, 2 * BATCH);   // 8 x 32 x 4 = 1024 blocks
    chamfer_min_kernel<<<gch, 256, 0, stream>>>(q1w, q2f, mins, part, store_mode);

    chamfer_reduce_kernel<<<dim3(2 * BATCH * N_PTS / 256), 256, 0, stream>>>(mins, part, out, store_mode);

    smooth_kernel<<<dim3(N_PTS / PPB, BATCH), 256, 0, stream>>>(q1f, flow, out);
}

// Round 8
// 151.910 us; speedup vs baseline: 1.0866x; 1.0866x over previous
//
#include <hip/hip_runtime.h>

#define N_PTS 8192
#define BATCH 2
#define KNN 8
#define STILE 2048          // smooth LDS tile (points)
#define PPB 16              // smooth points per block (4 waves x 4 pts)
#define CH_R 8              // chamfer rows per thread
#define CH_SLICE 256        // chamfer candidates per block
#define NSLICE (N_PTS / CH_SLICE)       // 32
#define CH_BLOCKS 512                   // 4 rowTiles x 32 slices x 4 combos
#define SM_BLOCKS (N_PTS / PPB * BATCH) // 1024
#define WS_STORE_NEED (4 * 1024 * 1024) // partial mins
#define OFF_MINS 0                      // fallback: 128 KiB mins at ws start

// ---------------- helpers ----------------
__device__ __forceinline__ void ce(unsigned &x, unsigned &y) {
    unsigned lo = min(x, y), hi = max(x, y); x = lo; y = hi;
}

__device__ __forceinline__ void insert4(unsigned o[4], unsigned key) {
    unsigned n0 = min(o[0], key);
    unsigned n1 = max(o[0], min(o[1], key));
    unsigned n2 = max(o[1], min(o[2], key));
    unsigned n3 = max(o[2], min(o[3], key));
    o[0]=n0; o[1]=n1; o[2]=n2; o[3]=n3;
}

__device__ __forceinline__ void merge_stage8(unsigned m[8], int d) {
    unsigned p[8], c[8];
    #pragma unroll
    for (int k = 0; k < 8; ++k) p[k] = __shfl_xor(m[k], d, 64);
    #pragma unroll
    for (int k = 0; k < 8; ++k) c[k] = min(m[k], p[7-k]);
    ce(c[0],c[4]); ce(c[1],c[5]); ce(c[2],c[6]); ce(c[3],c[7]);
    ce(c[0],c[2]); ce(c[1],c[3]); ce(c[4],c[6]); ce(c[5],c[7]);
    ce(c[0],c[1]); ce(c[2],c[3]); ce(c[4],c[5]); ce(c[6],c[7]);
    #pragma unroll
    for (int k = 0; k < 8; ++k) m[k] = c[k];
}

__device__ __forceinline__ void merge64(unsigned m[8]) {
    merge_stage8(m, 1); merge_stage8(m, 2); merge_stage8(m, 4);
    merge_stage8(m, 8); merge_stage8(m, 16); merge_stage8(m, 32);
}

// ---------------- mega: chamfer slice blocks + smooth blocks ----------------
__global__ __launch_bounds__(256, 4) void mega_kernel(
        const float* __restrict__ pc1, const float* __restrict__ pc2,
        const float* __restrict__ flow, float* __restrict__ part,
        unsigned* __restrict__ mins, float* __restrict__ out, int store_mode) {
    __shared__ float4 sq[STILE];   // 32 KiB (chamfer uses sq[0..255] + scratch)
    const int tid = threadIdx.x;
    const int bx = blockIdx.x;

    if (bx < CH_BLOCKS) {
        // ================= chamfer role =================
        const int rt    = bx & 3;           // row tile (2048 rows)
        const int slice = (bx >> 2) & 31;   // candidate slice (256 cands)
        const int z     = bx >> 7;          // combo: b + 2*dir
        const int b = z & 1, dir = z >> 1;
        const float* P1 = pc1  + (size_t)b * N_PTS * 3;
        const float* P2 = pc2  + (size_t)b * N_PTS * 3;
        const float* FL = flow + (size_t)b * N_PTS * 3;
        const int m0 = slice * CH_SLICE;

        // stage 256 candidates (x,y,z,|q|^2) into sq[0..255]
        float* sraw = (float*)(sq + 256);   // 3 KiB scratch inside sq buffer
        if (tid < CH_SLICE * 3 / 4) {
            float4 v;
            if (dir == 0) {
                v = ((const float4*)(P2 + (size_t)m0 * 3))[tid];
            } else {
                float4 a = ((const float4*)(P1 + (size_t)m0 * 3))[tid];
                float4 f = ((const float4*)(FL + (size_t)m0 * 3))[tid];
                v = make_float4(a.x + f.x, a.y + f.y, a.z + f.z, a.w + f.w);
            }
            ((float4*)sraw)[tid] = v;
        }

        const int i0 = rt * (256 * CH_R) + tid * CH_R;
        float mx[CH_R], my_[CH_R], mz_[CH_R], p2[CH_R], best[CH_R];
        #pragma unroll
        for (int r = 0; r < CH_R; ++r) {
            int row = i0 + r;
            float px, py, pz;
            if (dir == 0) {
                px = P1[row*3+0] + FL[row*3+0];
                py = P1[row*3+1] + FL[row*3+1];
                pz = P1[row*3+2] + FL[row*3+2];
            } else {
                px = P2[row*3+0]; py = P2[row*3+1]; pz = P2[row*3+2];
            }
            mx[r] = -2.0f * px; my_[r] = -2.0f * py; mz_[r] = -2.0f * pz;
            p2[r] = fmaf(px, px, fmaf(py, py, pz * pz));
            best[r] = __builtin_inff();
        }
        __syncthreads();
        {
            float qx = sraw[tid*3+0], qy = sraw[tid*3+1], qz = sraw[tid*3+2];
            sq[tid] = make_float4(qx, qy, qz, fmaf(qx, qx, fmaf(qy, qy, qz * qz)));
        }
        __syncthreads();

        #pragma unroll 8
        for (int jj = 0; jj < CH_SLICE; ++jj) {
            float4 q = sq[jj];
            #pragma unroll
            for (int r = 0; r < CH_R; ++r) {
                float s = fmaf(mx[r], q.x, fmaf(my_[r], q.y, fmaf(mz_[r], q.z, q.w)));
                best[r] = fminf(best[r], s);
            }
        }

        float d2v[CH_R];
        #pragma unroll
        for (int r = 0; r < CH_R; ++r) d2v[r] = fmaxf(best[r] + p2[r], 0.0f);
        if (store_mode) {
            float* dst = part + ((size_t)(z * NSLICE + slice)) * N_PTS + i0;
            *(float4*)(dst)     = make_float4(d2v[0], d2v[1], d2v[2], d2v[3]);
            *(float4*)(dst + 4) = make_float4(d2v[4], d2v[5], d2v[6], d2v[7]);
        } else {
            #pragma unroll
            for (int r = 0; r < CH_R; ++r)
                atomicMin(&mins[z * N_PTS + i0 + r], __float_as_uint(d2v[r]));
        }
    } else {
        // ================= smooth role =================
        const int s  = bx - CH_BLOCKS;
        const int b  = s >> 9;               // batch
        const int sx = s & 511;
        const int wv = tid >> 6, lane = tid & 63;
        const int i0w = sx * PPB + wv * 4;   // wave's 4 points
        const float* P = pc1  + (size_t)b * N_PTS * 3;
        const float* F = flow + (size_t)b * N_PTS * 3;

        float mx[4], my[4], mz[4], p2[4], gr[4];
        unsigned thr[4];
        #pragma unroll
        for (int r = 0; r < 4; ++r) {
            int i = i0w + r;
            float px = P[i*3+0], py = P[i*3+1], pz = P[i*3+2];
            mx[r] = -2.0f * px; my[r] = -2.0f * py; mz[r] = -2.0f * pz;
            p2[r] = fmaf(px, px, fmaf(py, py, pz * pz));
            gr[r] = __builtin_inff();
            thr[r] = 0xFFFFFFFFu;
        }

        unsigned o[4][4];
        #pragma unroll
        for (int r = 0; r < 4; ++r)
            #pragma unroll
            for (int k = 0; k < 4; ++k) o[r][k] = 0xFFFFFFFFu;

        __shared__ float psum[4];

        #pragma unroll 1
        for (int tile = 0; tile < N_PTS / STILE; ++tile) {   // 4 tiles
            const int t0 = tile * STILE;
            __syncthreads();
            #pragma unroll
            for (int u = tid; u < STILE; u += 256) {
                int g = t0 + u;
                float qx = P[g*3+0], qy = P[g*3+1], qz = P[g*3+2];
                sq[u] = make_float4(qx, qy, qz, fmaf(qx, qx, fmaf(qy, qy, qz * qz)));
            }
            __syncthreads();

            if (tile == 0) {
                #pragma unroll 4
                for (int st = 0; st < STILE / 64; ++st) {
                    float4 qa = sq[st * 64 + lane];
                    int j = st * 64 + lane;
                    #pragma unroll
                    for (int r = 0; r < 4; ++r) {
                        float ss = fmaf(mx[r], qa.x, fmaf(my[r], qa.y, fmaf(mz[r], qa.z, qa.w)));
                        float d2 = fmaxf(ss + p2[r], 0.0f);
                        unsigned key = (__float_as_uint(d2) & 0xFFFFE000u) | (unsigned)j;
                        key = (j == i0w + r) ? 0xFFFFFFFFu : key;  // self-mask
                        insert4(o[r], key);
                    }
                }
            } else {
                #pragma unroll 4
                for (int st = 0; st < STILE / 64; ++st) {
                    float4 qa = sq[st * 64 + lane];
                    int j = t0 + st * 64 + lane;
                    float s0 = fmaf(mx[0], qa.x, fmaf(my[0], qa.y, fmaf(mz[0], qa.z, qa.w)));
                    float s1 = fmaf(mx[1], qa.x, fmaf(my[1], qa.y, fmaf(mz[1], qa.z, qa.w)));
                    float s2 = fmaf(mx[2], qa.x, fmaf(my[2], qa.y, fmaf(mz[2], qa.z, qa.w)));
                    float s3 = fmaf(mx[3], qa.x, fmaf(my[3], qa.y, fmaf(mz[3], qa.z, qa.w)));
                    if (__any(s0 <= gr[0])) {
                        float d2 = fmaxf(s0 + p2[0], 0.0f);
                        unsigned key = (__float_as_uint(d2) & 0xFFFFE000u) | (unsigned)j;
                        key = (j == i0w + 0) ? 0xFFFFFFFFu : key;
                        insert4(o[0], key);
                    }
                    if (__any(s1 <= gr[1])) {
                        float d2 = fmaxf(s1 + p2[1], 0.0f);
                        unsigned key = (__float_as_uint(d2) & 0xFFFFE000u) | (unsigned)j;
                        key = (j == i0w + 1) ? 0xFFFFFFFFu : key;
                        insert4(o[1], key);
                    }
                    if (__any(s2 <= gr[2])) {
                        float d2 = fmaxf(s2 + p2[2], 0.0f);
                        unsigned key = (__float_as_uint(d2) & 0xFFFFE000u) | (unsigned)j;
                        key = (j == i0w + 2) ? 0xFFFFFFFFu : key;
                        insert4(o[2], key);
                    }
                    if (__any(s3 <= gr[3])) {
                        float d2 = fmaxf(s3 + p2[3], 0.0f);
                        unsigned key = (__float_as_uint(d2) & 0xFFFFE000u) | (unsigned)j;
                        key = (j == i0w + 3) ? 0xFFFFFFFFu : key;
                        insert4(o[3], key);
                    }
                }
            }

            if (tile <= 2) {
                // valid 8th-bound: min over lane-pairs of max(o[3]_l, o[3]_{l^1});
                // any 8 distinct real keys (lists are self-free) bound the true 8th.
                #pragma unroll
                for (int r = 0; r < 4; ++r) {
                    unsigned a = max(o[r][3], (unsigned)__shfl_xor((int)o[r][3], 1, 64));
                    a = min(a, (unsigned)__shfl_xor((int)a, 2, 64));
                    a = min(a, (unsigned)__shfl_xor((int)a, 4, 64));
                    a = min(a, (unsigned)__shfl_xor((int)a, 8, 64));
                    a = min(a, (unsigned)__shfl_xor((int)a, 16, 64));
                    a = min(a, (unsigned)__shfl_xor((int)a, 32, 64));
                    thr[r] = min(thr[r], a);
                    // +2 truncation-buckets slack: gate passes superset of key<=thr
                    float thr_up = __uint_as_float((thr[r] & 0xFFFFE000u) + 0x4000u);
                    gr[r] = thr_up - p2[r];
                }
            }
        }

        unsigned fin[4][8];
        #pragma unroll
        for (int r = 0; r < 4; ++r) {
            unsigned m[8] = {o[r][0], o[r][1], o[r][2], o[r][3],
                             0xFFFFFFFFu, 0xFFFFFFFFu, 0xFFFFFFFFu, 0xFFFFFFFFu};
            merge64(m);
            #pragma unroll
            for (int k = 0; k < 8; ++k) fin[r][k] = m[k];
        }

        const int sel = lane & 31;
        unsigned key = fin[0][0];
        #pragma unroll
        for (int rr = 0; rr < 4; ++rr)
            #pragma unroll
            for (int kk = 0; kk < 8; ++kk)
                if (sel == rr * 8 + kk) key = fin[rr][kk];
        const int r = sel >> 3;
        const int i = i0w + r;
        const int j = (int)(key & (N_PTS - 1));
        float dx = F[i*3+0] - F[j*3+0];
        float dy = F[i*3+1] - F[j*3+1];
        float dz = F[i*3+2] - F[j*3+2];
        float sv = sqrtf(fmaf(dx, dx, fmaf(dy, dy, dz * dz)));
        #pragma unroll
        for (int d = 1; d < 64; d <<= 1) sv += __shfl_xor(sv, d, 64);
        if (lane == 0) psum[wv] = sv;
        __syncthreads();
        if (tid == 0) {
            // W_SMOOTH(0.5) * 1/2 (lane duplication) / (B*N*K)
            atomicAdd(out, (psum[0] + psum[1] + psum[2] + psum[3]) *
                           (0.25f / ((float)BATCH * N_PTS * KNN)));
        }
    }
}

// ---------------- chamfer reduce: min over slices, sqrt, mean ----------------
__global__ void chamfer_reduce_kernel(const unsigned* __restrict__ mins,
                                      const float* __restrict__ part,
                                      float* __restrict__ out, int store_mode) {
    int t = blockIdx.x * 256 + threadIdx.x;   // 0..32767 = combo*8192+row
    float v;
    if (store_mode) {
        int c = t >> 13, row = t & (N_PTS - 1);
        const float* p = part + ((size_t)c * NSLICE) * N_PTS + row;
        v = __builtin_inff();
        #pragma unroll 8
        for (int s = 0; s < NSLICE; ++s) v = fminf(v, p[(size_t)s * N_PTS]);
    } else {
        v = __uint_as_float(mins[t]);
    }
    float d = sqrtf(v) * (1.0f / (float)(BATCH * N_PTS));
    #pragma unroll
    for (int off = 32; off > 0; off >>= 1) d += __shfl_down(d, off, 64);
    __shared__ float wsum[4];
    int wid = threadIdx.x >> 6;
    if ((threadIdx.x & 63) == 0) wsum[wid] = d;
    __syncthreads();
    if (threadIdx.x == 0) atomicAdd(out, wsum[0] + wsum[1] + wsum[2] + wsum[3]);
}

extern "C" void kernel_launch(void* const* d_in, const int* in_sizes, int n_in,
                              void* d_out, int out_size, void* d_ws, size_t ws_size,
                              hipStream_t stream) {
    const float* pc1  = (const float*)d_in[0];
    const float* pc2  = (const float*)d_in[1];
    const float* flow = (const float*)d_in[2];
    float* out = (float*)d_out;
    float* part = (float*)d_ws;               // 4 MiB partial mins
    unsigned* mins = (unsigned*)((char*)d_ws + OFF_MINS);  // fallback aliases ws

    const int store_mode = (ws_size >= (size_t)WS_STORE_NEED) ? 1 : 0;

    hipMemsetAsync(out, 0, sizeof(float), stream);
    if (!store_mode) {
        hipMemsetAsync(mins, 0xFF, 4u * N_PTS * sizeof(unsigned), stream);  // fallback init
    }

    mega_kernel<<<dim3(CH_BLOCKS + SM_BLOCKS), 256, 0, stream>>>(
        pc1, pc2, flow, part, mins, out, store_mode);

    chamfer_reduce_kernel<<<dim3(2 * BATCH * N_PTS / 256), 256, 0, stream>>>(
        mins, part, out, store_mode);
}